// Round 1
// baseline (751.795 us; speedup 1.0000x reference)
//
#include <hip/hip_runtime.h>

#define HW 128
#define GNUM 2
#define BATCH 4
// off_ws: G*B*H*W*18 floats
#define OFF_WS_FLOATS (GNUM * BATCH * HW * HW * 18)

// ---------------------------------------------------------------------------
// K0: combined bias  bias2[g][f] = pw_b[g,f] + sum_kin pw_w[g,kin,f]*dw_b[g,kin]
// ---------------------------------------------------------------------------
__global__ void bias_kernel(const float* __restrict__ pw_w,
                            const float* __restrict__ pw_b,
                            const float* __restrict__ dw_b,
                            float* __restrict__ bias2) {
    int g = blockIdx.x;
    int f = threadIdx.x;
    float acc = pw_b[g * 64 + f];
    for (int kin = 0; kin < 576; ++kin)
        acc += pw_w[(g * 576 + kin) * 64 + f] * dw_b[g * 576 + kin];
    bias2[g * 64 + f] = acc;
}

// ---------------------------------------------------------------------------
// K1: offset conv (3x3 SAME, Cg=64 -> 18) per group.
// 16x16 pixel tile, halo 18x18, channels in two halves of 32 (LDS budget).
// tile stride 33 (=32+1 pad) for bank spread.
// ---------------------------------------------------------------------------
__global__ __launch_bounds__(256) void offset_kernel(
    const float* __restrict__ x, const float* __restrict__ off_w,
    const float* __restrict__ off_b, float* __restrict__ off_ws) {
    __shared__ float tile[324 * 33];  // 18*18 positions * 33 (32ch + pad)
    const int tileIdx = blockIdx.x;   // 8x8 tiles of 16x16
    const int b = blockIdx.y, g = blockIdx.z;
    const int h0 = (tileIdx >> 3) * 16, w0 = (tileIdx & 7) * 16;
    const int t = threadIdx.x;
    const int px = t & 15, py = t >> 4;

    float acc[18];
#pragma unroll
    for (int o = 0; o < 18; ++o) acc[o] = off_b[g * 18 + o];

    for (int half = 0; half < 2; ++half) {
        __syncthreads();
        for (int i = t; i < 324 * 32; i += 256) {
            int sp = i >> 5, c = i & 31;
            int sy = sp / 18, sx = sp - sy * 18;
            int gy = h0 - 1 + sy, gx = w0 - 1 + sx;
            float v = 0.f;
            if (gy >= 0 && gy < HW && gx >= 0 && gx < HW)
                v = x[(((b * HW + gy) * HW + gx) << 7) + g * 64 + half * 32 + c];
            tile[sp * 33 + c] = v;
        }
        __syncthreads();
#pragma unroll
        for (int ky = 0; ky < 3; ++ky)
#pragma unroll
            for (int kx = 0; kx < 3; ++kx) {
                const float* wp =
                    off_w + (((g * 3 + ky) * 3 + kx) * 64 + half * 32) * 18;
                const float* tp = tile + ((py + ky) * 18 + px + kx) * 33;
                for (int c = 0; c < 32; ++c) {
                    float v = tp[c];
#pragma unroll
                    for (int o = 0; o < 18; ++o) acc[o] += v * wp[c * 18 + o];
                }
            }
    }
    float* op = off_ws +
                (((g * BATCH + b) * HW * HW + (h0 + py) * HW + (w0 + px)) * 18);
#pragma unroll
    for (int o = 0; o < 18; ++o) op[o] = acc[o];
}

// ---------------------------------------------------------------------------
// K2: fused bilinear-sample -> depthwise 3x3 -> pointwise 576->64, per tap j.
// Block = 256 threads = one 8x8 output tile of one (b, g).
//   samp: 10x10 halo pixels x 64 ch, stride 68 (16B-aligned float4, bank spread)
//   dwl : depthwise output as [c][p] (64x64), conflict-free write & read
// acc: thread (p = t&63, fb = (t>>6)*16) holds out[p][fb..fb+15].
// ---------------------------------------------------------------------------
__global__ __launch_bounds__(256) void deform_kernel(
    const float* __restrict__ x, const float* __restrict__ off_ws,
    const float* __restrict__ dw_w, const float* __restrict__ pw_w,
    const float* __restrict__ bias2, float* __restrict__ out) {
    __shared__ float samp[100 * 68];  // 27200 B
    __shared__ float dwl[64 * 64];    // 16384 B
    const int tileIdx = blockIdx.x;   // 16x16 tiles of 8x8
    const int b = blockIdx.y, g = blockIdx.z;
    const int h0 = (tileIdx >> 4) * 8, w0 = (tileIdx & 15) * 8;
    const int t = threadIdx.x;
    const int lane = t & 63;
    const int wv = __builtin_amdgcn_readfirstlane(t >> 6);  // wave id 0..3
    const int fb = wv << 4;                                 // 16 output f's
    const int p = lane;                                     // pixel in 8x8
    const int ayp = p >> 3, axp = p & 7;
    const float* xg = x + g * 64;

    float acc[16];
#pragma unroll
    for (int u = 0; u < 16; ++u) acc[u] = bias2[g * 64 + fb + u];

    for (int j = 0; j < 9; ++j) {
        const int jy = j / 3, jx = j - jy * 3;
        __syncthreads();
        // ---- Phase S: bilinear-sample tap j into samp (sp wave-uniform, lane=ch)
        for (int k = 0; k < 25; ++k) {
            int sp = wv + (k << 2);  // 0..99, uniform per wave
            int spy = sp / 10, spx = sp - spy * 10;
            int gy = h0 - 1 + spy, gx = w0 - 1 + spx;
            float val = 0.f;
            if (gy >= 0 && gy < HW && gx >= 0 && gx < HW) {
                const float* ofp =
                    off_ws +
                    (((g * BATCH + b) * HW * HW + gy * HW + gx) * 18 + 2 * j);
                float ox = ofp[0], oy = ofp[1];
                float xf = fminf(fmaxf((float)(gx + jx - 1) + ox, 0.f), 127.f);
                float yf = fminf(fmaxf((float)(gy + jy - 1) + oy, 0.f), 127.f);
                float x0 = floorf(xf), y0 = floorf(yf);
                float x1 = fminf(x0 + 1.f, 127.f);
                float y1 = fminf(y0 + 1.f, 127.f);
                float wa = (x1 - xf) * (y1 - yf);
                float wb = (x1 - xf) * (yf - y0);
                float wc = (xf - x0) * (y1 - yf);
                float wd = (xf - x0) * (yf - y0);
                int x0i = (int)x0, y0i = (int)y0;
                int x1i = (int)x1, y1i = (int)y1;
                float va = xg[(((b * HW + y0i) * HW + x0i) << 7) + lane];
                float vb = xg[(((b * HW + y1i) * HW + x0i) << 7) + lane];
                float vc = xg[(((b * HW + y0i) * HW + x1i) << 7) + lane];
                float vd = xg[(((b * HW + y1i) * HW + x1i) << 7) + lane];
                val = wa * va + wb * vb + wc * vc + wd * vd;
            }
            samp[sp * 68 + lane] = val;
        }
        __syncthreads();
        // ---- Phase A: depthwise 3x3 for channels [fb, fb+16), all via float4
        {
#pragma unroll
            for (int cq = 0; cq < 4; ++cq) {
                int c = fb + (cq << 2);
                float4 d = make_float4(0.f, 0.f, 0.f, 0.f);
#pragma unroll
                for (int ky = 0; ky < 3; ++ky)
#pragma unroll
                    for (int kx = 0; kx < 3; ++kx) {
                        const float4 v = *(const float4*)&samp
                            [((ayp + ky) * 10 + axp + kx) * 68 + c];
                        const float4 w = *(const float4*)&dw_w
                            [((g * 3 + ky) * 3 + kx) * 576 + (j << 6) + c];
                        d.x += v.x * w.x;
                        d.y += v.y * w.y;
                        d.z += v.z * w.z;
                        d.w += v.w * w.w;
                    }
                dwl[(c + 0) * 64 + p] = d.x;
                dwl[(c + 1) * 64 + p] = d.y;
                dwl[(c + 2) * 64 + p] = d.z;
                dwl[(c + 3) * 64 + p] = d.w;
            }
        }
        __syncthreads();
        // ---- Phase B: pointwise GEMM accumulate (16 fma per ds_read)
        for (int c = 0; c < 64; ++c) {
            float v = dwl[(c << 6) + p];
            const float* wp = pw_w + (((g * 576 + (j << 6) + c) << 6) + fb);
#pragma unroll
            for (int u = 0; u < 16; ++u) acc[u] += v * wp[u];
        }
    }
    // ---- store: 16 consecutive f's per thread as 4x float4
    float* op = out + ((((b * HW + h0 + ayp) * HW + w0 + axp)) << 7) + g * 64 + fb;
#pragma unroll
    for (int u = 0; u < 16; u += 4)
        *(float4*)&op[u] = make_float4(acc[u], acc[u + 1], acc[u + 2], acc[u + 3]);
}

extern "C" void kernel_launch(void* const* d_in, const int* in_sizes, int n_in,
                              void* d_out, int out_size, void* d_ws,
                              size_t ws_size, hipStream_t stream) {
    const float* x = (const float*)d_in[0];
    const float* off_w = (const float*)d_in[1];
    const float* off_b = (const float*)d_in[2];
    const float* dw_w = (const float*)d_in[3];
    const float* dw_b = (const float*)d_in[4];
    const float* pw_w = (const float*)d_in[5];
    const float* pw_b = (const float*)d_in[6];

    float* wsf = (float*)d_ws;
    float* off_ws = wsf;                    // 9.44 MB
    float* bias2 = wsf + OFF_WS_FLOATS;     // 128 floats

    bias_kernel<<<dim3(GNUM), dim3(64), 0, stream>>>(pw_w, pw_b, dw_b, bias2);
    offset_kernel<<<dim3(64, BATCH, GNUM), dim3(256), 0, stream>>>(
        x, off_w, off_b, off_ws);
    deform_kernel<<<dim3(256, BATCH, GNUM), dim3(256), 0, stream>>>(
        x, off_ws, dw_w, pw_w, bias2, (float*)d_out);
}